// Round 4
// baseline (1004.610 us; speedup 1.0000x reference)
//
#include <hip/hip_runtime.h>
#include <math.h>

typedef _Float16 f16;
typedef _Float16 f16x8 __attribute__((ext_vector_type(8)));
typedef float f32x4 __attribute__((ext_vector_type(4)));
typedef unsigned int uint32;
typedef unsigned short ushort16;

#define NSAMP 131072
#define DD 12
#define LLAYERS 4
#define KK 8
#define BV 3.0f
#define SLP 0.2f
#define BLK 256
#define NLW 17920   // f16 elems per (net,layer) in ws: 512 (W0) + 8192 (Wh) + 9216 (Wl)
#define WS_WH 512
#define WS_WL 8704

__device__ __forceinline__ float leaky(float v){ return v >= 0.f ? v : SLP * v; }

__device__ __forceinline__ uint32 packh(float a, float b){
    union { f16 h; ushort16 u; } x, y;
    x.h = (f16)a; y.h = (f16)b;
    return (uint32)x.u | ((uint32)y.u << 16);
}
__device__ __forceinline__ float unpl(uint32 v){ union { ushort16 u; f16 h; } c; c.u = (ushort16)v; return (float)c.h; }
__device__ __forceinline__ float unph(uint32 v){ union { ushort16 u; f16 h; } c; c.u = (ushort16)(v >> 16); return (float)c.h; }

__device__ __forceinline__ f32x4 MF(f16x8 a, f16x8 b, f32x4 c){
    return __builtin_amdgcn_mfma_f32_16x16x32_f16(a, b, c, 0, 0, 0);
}

// act tile: per-wave [64 samples][64 feats] f16, row=128B, XOR-swizzled by ((s&7)<<4)
__device__ __forceinline__ const f16x8* actRd(const f16* actW, int s, int fb){
    return (const f16x8*)((const char*)actW + s * 128 + (fb ^ ((s & 7) << 4)));
}
__device__ __forceinline__ uint2* actWr(f16* actW, int s, int fb){
    return (uint2*)((char*)actW + s * 128 + (fb ^ ((s & 7) << 4)));
}

// ---------------- prep kernel: split weights into fp16 hi/lo, fragment-ordered ----------------
extern "C" __global__ void nsflow_prep(const float* __restrict__ n1W0, const float* __restrict__ n1Wh, const float* __restrict__ n1Wl,
                                       const float* __restrict__ n2W0, const float* __restrict__ n2Wh, const float* __restrict__ n2Wl,
                                       const float* __restrict__ c1W0, const float* __restrict__ c1Wh, const float* __restrict__ c1Wl,
                                       const float* __restrict__ c2W0, const float* __restrict__ c2Wh, const float* __restrict__ c2Wl,
                                       f16* __restrict__ ws_hi, f16* __restrict__ ws_lo){
    int NL = blockIdx.y;                     // l*4 + net, net: 0=c1 1=n1 2=c2 3=n2
    int off = blockIdx.x * 256 + threadIdx.x; // 0..17919
    int layer = NL >> 2, net = NL & 3;
    const float *W0, *Wh, *Wl; int nin;
    if (net == 0){ W0 = c1W0; Wh = c1Wh; Wl = c1Wl; nin = 4; }
    else if (net == 1){ W0 = n1W0; Wh = n1Wh; Wl = n1Wl; nin = 6; }
    else if (net == 2){ W0 = c2W0; Wh = c2Wh; Wl = c2Wl; nin = 4; }
    else { W0 = n2W0; Wh = n2Wh; Wl = n2Wl; nin = 6; }

    float w = 0.f;
    if (off < 512){                          // W0^T frags: [mt(4)][16 lanes][8 j]
        int mt = off >> 7, r = off & 127, ln = r >> 3, j = r & 7;
        int row = mt * 16 + ln;              // row = f_out
        if (j < nin) w = W0[(layer * nin + j) * 64 + row];
    } else if (off < 8704){                  // Wh^T frags: [h(2)][mt*2+ks (8)][64 lanes][8 j]
        int o = off - 512; int h = o >> 12; o &= 4095;
        int t = o >> 9, ln = (o >> 3) & 63, j = o & 7;
        int mt = t >> 1, ks = t & 1;
        int k = ks * 32 + (ln >> 4) * 8 + j, row = mt * 16 + (ln & 15);
        w = Wh[((layer * 2 + h) * 64 + k) * 64 + row];
    } else {                                 // Wl^T frags: [mt*2+ks (18)][64 lanes][8 j]
        int o = off - 8704;
        int t = o >> 9, ln = (o >> 3) & 63, j = o & 7;
        int mt = t >> 1, ks = t & 1;
        int k = ks * 32 + (ln >> 4) * 8 + j, row = mt * 16 + (ln & 15);
        if (row < 138) w = Wl[(layer * 64 + k) * 138 + row];
    }
    f16 hi = (f16)w;
    f16 lo = (f16)(w - (float)hi);
    ws_hi[NL * NLW + off] = hi;
    ws_lo[NL * NLW + off] = lo;
}

// ---------------- GEMM helpers (per wave, in-place act tile) ----------------
// first layer, conditioner input (4 feats, stride-4 LDS rows, zero-fill k>=4)
__device__ __forceinline__ void gemmL0c(const f16* __restrict__ ah, const f16* __restrict__ al,
                                        const float* __restrict__ bias,
                                        const f16* src, f16* actW, int lane, int widS){
    int l15 = lane & 15, g = lane >> 4;
    f16x8 Z = {};
    f16x8 Bf[4];
#pragma unroll
    for (int nt = 0; nt < 4; ++nt){
        union { uint2 u; f16 h[4]; } cc;
        cc.u = *(const uint2*)(src + (widS + nt * 16 + l15) * 4);
        f16x8 B = Z;
        B[0] = cc.h[0]; B[1] = cc.h[1]; B[2] = cc.h[2]; B[3] = cc.h[3];
        Bf[nt] = B;
    }
    float blv[4][4];
#pragma unroll
    for (int mt = 0; mt < 4; ++mt)
#pragma unroll
        for (int i = 0; i < 4; ++i) blv[mt][i] = bias[mt * 16 + g * 4 + i];
    bool g0 = (g == 0);
#pragma unroll
    for (int mt = 0; mt < 4; ++mt){
        f16x8 Ah = g0 ? *(const f16x8*)(ah + (mt * 16 + l15) * 8) : Z;
        f16x8 Al = g0 ? *(const f16x8*)(al + (mt * 16 + l15) * 8) : Z;
#pragma unroll
        for (int nt = 0; nt < 4; ++nt){
            f32x4 acc = {0.f, 0.f, 0.f, 0.f};
            acc = MF(Ah, Bf[nt], acc);
            acc = MF(Al, Bf[nt], acc);
            float h0 = leaky(acc[0] + blv[mt][0]);
            float h1 = leaky(acc[1] + blv[mt][1]);
            float h2 = leaky(acc[2] + blv[mt][2]);
            float h3 = leaky(acc[3] + blv[mt][3]);
            uint2 v = { packh(h0, h1), packh(h2, h3) };
            *actWr(actW, nt * 16 + l15, mt * 32 + g * 8) = v;
        }
    }
}

// first layer, data input (6 feats from xst rows, stride 16, slots half*8..half*8+7)
__device__ __forceinline__ void gemmL0n(const f16* __restrict__ ah, const f16* __restrict__ al,
                                        const float* __restrict__ bias,
                                        const f16* src, int offE,
                                        f16* actW, int lane, int widS){
    int l15 = lane & 15, g = lane >> 4;
    f16x8 Z = {};
    f16x8 Bf[4];
#pragma unroll
    for (int nt = 0; nt < 4; ++nt)
        Bf[nt] = *(const f16x8*)(src + (widS + nt * 16 + l15) * 16 + offE);
    float blv[4][4];
#pragma unroll
    for (int mt = 0; mt < 4; ++mt)
#pragma unroll
        for (int i = 0; i < 4; ++i) blv[mt][i] = bias[mt * 16 + g * 4 + i];
    bool g0 = (g == 0);
#pragma unroll
    for (int mt = 0; mt < 4; ++mt){
        f16x8 Ah = g0 ? *(const f16x8*)(ah + (mt * 16 + l15) * 8) : Z;
        f16x8 Al = g0 ? *(const f16x8*)(al + (mt * 16 + l15) * 8) : Z;
#pragma unroll
        for (int nt = 0; nt < 4; ++nt){
            f32x4 acc = {0.f, 0.f, 0.f, 0.f};
            acc = MF(Ah, Bf[nt], acc);
            acc = MF(Al, Bf[nt], acc);
            float h0 = leaky(acc[0] + blv[mt][0]);
            float h1 = leaky(acc[1] + blv[mt][1]);
            float h2 = leaky(acc[2] + blv[mt][2]);
            float h3 = leaky(acc[3] + blv[mt][3]);
            uint2 v = { packh(h0, h1), packh(h2, h3) };
            *actWr(actW, nt * 16 + l15, mt * 32 + g * 8) = v;
        }
    }
}

// hidden 64->64 layer, in place (all B fragments pre-loaded before first write)
__device__ __forceinline__ void gemm64(const f16* __restrict__ ah, const f16* __restrict__ al,
                                       const float* __restrict__ bias,
                                       f16* actW, int lane){
    int l15 = lane & 15, g = lane >> 4;
    f16x8 Bf[4][2];
#pragma unroll
    for (int nt = 0; nt < 4; ++nt)
#pragma unroll
        for (int ks = 0; ks < 2; ++ks)
            Bf[nt][ks] = *actRd(actW, nt * 16 + l15, ks * 64 + g * 16);
    float blv[4][4];
#pragma unroll
    for (int mt = 0; mt < 4; ++mt)
#pragma unroll
        for (int i = 0; i < 4; ++i) blv[mt][i] = bias[mt * 16 + g * 4 + i];
#pragma unroll
    for (int mt = 0; mt < 4; ++mt){
        f16x8 Ah0 = *(const f16x8*)(ah + ((mt * 2 + 0) * 64 + lane) * 8);
        f16x8 Ah1 = *(const f16x8*)(ah + ((mt * 2 + 1) * 64 + lane) * 8);
        f16x8 Al0 = *(const f16x8*)(al + ((mt * 2 + 0) * 64 + lane) * 8);
        f16x8 Al1 = *(const f16x8*)(al + ((mt * 2 + 1) * 64 + lane) * 8);
#pragma unroll
        for (int nt = 0; nt < 4; ++nt){
            f32x4 acc = {0.f, 0.f, 0.f, 0.f};
            acc = MF(Ah0, Bf[nt][0], acc);
            acc = MF(Al0, Bf[nt][0], acc);
            acc = MF(Ah1, Bf[nt][1], acc);
            acc = MF(Al1, Bf[nt][1], acc);
            float h0 = leaky(acc[0] + blv[mt][0]);
            float h1 = leaky(acc[1] + blv[mt][1]);
            float h2 = leaky(acc[2] + blv[mt][2]);
            float h3 = leaky(acc[3] + blv[mt][3]);
            uint2 v = { packh(h0, h1), packh(h2, h3) };
            *actWr(actW, nt * 16 + l15, mt * 32 + g * 8) = v;
        }
    }
}

// final layer (conditioner): 64 -> 144(pad of 138), result kept packed in regs
__device__ __forceinline__ void gemmFinC(const f16* __restrict__ ah, const f16* __restrict__ al,
                                         const float* __restrict__ bias,
                                         const f16* actW, int lane, uint2 (&tcp)[9][4]){
    int l15 = lane & 15, g = lane >> 4;
    float blv[9][4];
#pragma unroll
    for (int mt = 0; mt < 9; ++mt)
#pragma unroll
        for (int i = 0; i < 4; ++i){
            int f = mt * 16 + g * 4 + i;
            blv[mt][i] = bias[f < 138 ? f : 137];
        }
#pragma unroll
    for (int nt = 0; nt < 4; ++nt){
        f16x8 B0 = *actRd(actW, nt * 16 + l15, g * 16);
        f16x8 B1 = *actRd(actW, nt * 16 + l15, 64 + g * 16);
#pragma unroll
        for (int mt = 0; mt < 9; ++mt){
            f16x8 Ah0 = *(const f16x8*)(ah + ((mt * 2 + 0) * 64 + lane) * 8);
            f16x8 Ah1 = *(const f16x8*)(ah + ((mt * 2 + 1) * 64 + lane) * 8);
            f16x8 Al0 = *(const f16x8*)(al + ((mt * 2 + 0) * 64 + lane) * 8);
            f16x8 Al1 = *(const f16x8*)(al + ((mt * 2 + 1) * 64 + lane) * 8);
            f32x4 acc = {0.f, 0.f, 0.f, 0.f};
            acc = MF(Ah0, B0, acc);
            acc = MF(Al0, B0, acc);
            acc = MF(Ah1, B1, acc);
            acc = MF(Al1, B1, acc);
            float h0 = leaky(acc[0] + blv[mt][0]);
            float h1 = leaky(acc[1] + blv[mt][1]);
            float h2 = leaky(acc[2] + blv[mt][2]);
            float h3 = leaky(acc[3] + blv[mt][3]);
            tcp[mt][nt].x = packh(h0, h1);
            tcp[mt][nt].y = packh(h2, h3);
        }
    }
}

// spline for one chunk of 16 samples; returns per-lane logdet contribution,
// butterfly-reduced so lane L holds the 6-dim sum for sample (sbase + (L&15)).
__device__ __forceinline__ float spline_chunk(const f16* thW, f16* xst,
                                              int sbase, int half, int lane){
    float vsum = 0.f;
#pragma unroll 1
    for (int pass = 0; pass < 2; ++pass){
        if (pass == 1 && lane >= 32) break;
        int dd = pass * 4 + (lane >> 4);
        int s16 = lane & 15;

        const f16* tr = thW + s16 * 144 + dd * 24;
        f16x8 t0 = *(const f16x8*)(tr);
        f16x8 t1 = *(const f16x8*)(tr + 8);
        f16x8 t2 = *(const f16x8*)(tr + 16);
        float th[23];
#pragma unroll
        for (int j = 0; j < 8; ++j) th[j] = (float)t0[j];
#pragma unroll
        for (int j = 0; j < 8; ++j) th[8 + j] = (float)t1[j];
#pragma unroll
        for (int j = 0; j < 7; ++j) th[16 + j] = (float)t2[j];

        // widths softmax * 2B
        float mw = th[0];
#pragma unroll
        for (int j = 1; j < KK; ++j) mw = fmaxf(mw, th[j]);
        float ew[KK]; float swsum = 0.f;
#pragma unroll
        for (int j = 0; j < KK; ++j){ ew[j] = __expf(th[j] - mw); swsum += ew[j]; }
        float iw_ = 6.0f / swsum;
        // heights softmax * 2B
        float mh = th[KK];
#pragma unroll
        for (int j = 1; j < KK; ++j) mh = fmaxf(mh, th[KK + j]);
        float eh[KK]; float shsum = 0.f;
#pragma unroll
        for (int j = 0; j < KK; ++j){ eh[j] = __expf(th[KK + j] - mh); shsum += eh[j]; }
        float ih_ = 6.0f / shsum;
        // derivs softplus, padded 1.0 ends
        float dv[KK + 1];
        dv[0] = 1.0f; dv[KK] = 1.0f;
#pragma unroll
        for (int j = 0; j < KK - 1; ++j){
            float v = th[2 * KK + j];
            float z = __expf(-fabsf(v));
            dv[j + 1] = fmaxf(v, 0.f) + __logf(1.0f + z);
        }

        int sidx = sbase + s16;
        int slot = half ? dd : 8 + dd;
        float X = (float)xst[sidx * 16 + slot];
        float Xc = fminf(fmaxf(X, -BV), BV);

        float cx = -BV, cy = -BV;
        float xk = -BV, xk1 = BV, yk = -BV, yk1 = BV, dk = 1.0f, dk1 = 1.0f;
#pragma unroll
        for (int j = 0; j < KK; ++j){
            float nx = (j == KK - 1) ? (BV + 1e-6f) : (cx + ew[j] * iw_);
            float ny = (j == KK - 1) ? BV : (cy + eh[j] * ih_);
            bool sel = (j == 0) || (Xc >= cx);
            if (sel){ xk = cx; xk1 = nx; yk = cy; yk1 = ny; dk = dv[j]; dk1 = dv[j + 1]; }
            cx = nx; cy = ny;
        }
        float idx_ = 1.0f / (xk1 - xk);
        float s_ = (yk1 - yk) * idx_;
        float xi = (Xc - xk) * idx_;
        float om = 1.0f - xi;
        float xo = xi * om;
        float den = s_ + (dk1 + dk - 2.0f * s_) * xo;
        float Y = yk + (yk1 - yk) * (s_ * xi * xi + dk * xo) / den;
        float dydx = s_ * s_ * (dk1 * xi * xi + 2.0f * s_ * xo + dk * om * om) / (den * den);
        bool inside = (X <= BV) && (X >= -BV);
        float Yo = inside ? Y : X;
        float ldv = inside ? __logf(dydx) : 0.f;
        xst[sidx * 16 + slot] = (f16)Yo;
        vsum += ldv;
    }
    vsum += __shfl_xor(vsum, 16, 64);
    vsum += __shfl_xor(vsum, 32, 64);
    return vsum;
}

// final layer (data net) + product + th staging + spline, per nt chunk (FULLY UNROLLED:
// tcp must be statically indexed or it spills to scratch — rule #20, R3 post-mortem)
__device__ __forceinline__ void gemmFinN(const f16* __restrict__ ah, const f16* __restrict__ al,
                                         const float* __restrict__ bias,
                                         const f16* actW, f16* thW, f16* xst,
                                         const uint2 (&tcp)[9][4], int lane, int widS, int half,
                                         float& logdet){
    int l15 = lane & 15, g = lane >> 4, g4 = g * 4;
    float blv[9][4];
#pragma unroll
    for (int mt = 0; mt < 9; ++mt)
#pragma unroll
        for (int i = 0; i < 4; ++i){
            int f = mt * 16 + g4 + i;
            blv[mt][i] = bias[f < 138 ? f : 137];
        }
#pragma unroll
    for (int nt = 0; nt < 4; ++nt){
        f16x8 B0 = *actRd(actW, nt * 16 + l15, g * 16);
        f16x8 B1 = *actRd(actW, nt * 16 + l15, 64 + g * 16);
#pragma unroll
        for (int mt = 0; mt < 9; ++mt){
            f16x8 Ah0 = *(const f16x8*)(ah + ((mt * 2 + 0) * 64 + lane) * 8);
            f16x8 Ah1 = *(const f16x8*)(ah + ((mt * 2 + 1) * 64 + lane) * 8);
            f16x8 Al0 = *(const f16x8*)(al + ((mt * 2 + 0) * 64 + lane) * 8);
            f16x8 Al1 = *(const f16x8*)(al + ((mt * 2 + 1) * 64 + lane) * 8);
            f32x4 acc = {0.f, 0.f, 0.f, 0.f};
            acc = MF(Ah0, B0, acc);
            acc = MF(Al0, B0, acc);
            acc = MF(Ah1, B1, acc);
            acc = MF(Al1, B1, acc);
            float tc0 = unpl(tcp[mt][nt].x), tc1 = unph(tcp[mt][nt].x);
            float tc2 = unpl(tcp[mt][nt].y), tc3 = unph(tcp[mt][nt].y);
            float tv[4];
            tv[0] = leaky(acc[0] + blv[mt][0]) * tc0;
            tv[1] = leaky(acc[1] + blv[mt][1]) * tc1;
            tv[2] = leaky(acc[2] + blv[mt][2]) * tc2;
            tv[3] = leaky(acc[3] + blv[mt][3]) * tc3;
#pragma unroll
            for (int i = 0; i < 4; ++i){
                int f = mt * 16 + g4 + i;
                if (f < 138){
                    int dd = (f * 357) >> 13;
                    int p = f - dd * 23;
                    thW[l15 * 144 + dd * 24 + p] = (f16)tv[i];
                }
            }
        }
        float v = spline_chunk(thW, xst, widS + nt * 16, half, lane);
        if ((lane >> 4) == nt) logdet += v;
    }
}

// ---------------- main kernel ----------------
extern "C" __global__ void __launch_bounds__(BLK, 2)
nsflow_main(const float* __restrict__ x_in, const float* __restrict__ xc_in,
            const float* __restrict__ convP, const float* __restrict__ convS,
            const float* __restrict__ convL, const float* __restrict__ convU,
            const float* __restrict__ n1b0, const float* __restrict__ n1bh, const float* __restrict__ n1bl,
            const float* __restrict__ n2b0, const float* __restrict__ n2bh, const float* __restrict__ n2bl,
            const float* __restrict__ c1b0, const float* __restrict__ c1bh, const float* __restrict__ c1bl,
            const float* __restrict__ c2b0, const float* __restrict__ c2bh, const float* __restrict__ c2bl,
            const f16* __restrict__ wsh, const f16* __restrict__ wsl,
            float* __restrict__ out){
    __shared__ float WcS[LLAYERS][DD][DD];
    __shared__ float ldcS;
    __shared__ f16 xcS[256 * 4];
    __shared__ f16 xstS[256 * 16];
    __shared__ f16 actS[4 * 64 * 64];
    __shared__ f16 thS[4 * 16 * 144];

    // conv W = P (L+I) (U+diag(S)) and conv logdet
    for (int e = threadIdx.x; e < LLAYERS * DD * DD; e += BLK){
        int l = e / (DD * DD);
        int r = e - l * DD * DD;
        int i = r / DD;
        int j = r - i * DD;
        const float* P = convP + l * DD * DD;
        const float* Lm = convL + l * DD * DD;
        const float* Um = convU + l * DD * DD;
        const float* Sv = convS + l * DD;
        float acc = 0.f;
        for (int a = 0; a < DD; ++a){
            float inner = 0.f;
            for (int bb = 0; bb < DD; ++bb){
                float m1 = (bb < a) ? Lm[a * DD + bb] : (bb == a ? 1.f : 0.f);
                float m2 = (j > bb) ? Um[bb * DD + j] : (j == bb ? Sv[j] : 0.f);
                inner = fmaf(m1, m2, inner);
            }
            acc = fmaf(P[i * DD + a], inner, acc);
        }
        WcS[l][i][j] = acc;
    }
    if (threadIdx.x == 0){
        float sacc = 0.f;
        for (int q = 0; q < LLAYERS * DD; ++q) sacc += __logf(fabsf(convS[q]));
        ldcS = sacc;
    }

    int tid0 = threadIdx.x;
    int lane = tid0 & 63, wid = tid0 >> 6, widS = wid * 64;
    int gsamp = blockIdx.x * BLK + tid0;

    float xr[DD];
    {
        const float4* xv = (const float4*)(x_in + (size_t)gsamp * DD);
        float4 a0 = xv[0], a1 = xv[1], a2 = xv[2];
        xr[0]=a0.x; xr[1]=a0.y; xr[2]=a0.z; xr[3]=a0.w;
        xr[4]=a1.x; xr[5]=a1.y; xr[6]=a1.z; xr[7]=a1.w;
        xr[8]=a2.x; xr[9]=a2.y; xr[10]=a2.z; xr[11]=a2.w;
        float4 c0 = *(const float4*)(xc_in + (size_t)gsamp * 4);
        uint2 cv = { packh(c0.x, c0.y), packh(c0.z, c0.w) };
        *(uint2*)(xcS + tid0 * 4) = cv;
    }
    __syncthreads();

    float logdet = ldcS;
    f16* actW = actS + wid * 4096;
    f16* thW = thS + wid * 2304;

#pragma unroll 1
    for (int l = 0; l < LLAYERS; ++l){
        if (l > 0){
            uint4 r0 = *(const uint4*)(xstS + tid0 * 16);
            uint4 r1 = *(const uint4*)(xstS + tid0 * 16 + 8);
            xr[0]=unpl(r0.x); xr[1]=unph(r0.x); xr[2]=unpl(r0.y); xr[3]=unph(r0.y);
            xr[4]=unpl(r0.z); xr[5]=unph(r0.z);
            xr[6]=unpl(r1.x); xr[7]=unph(r1.x); xr[8]=unpl(r1.y); xr[9]=unph(r1.y);
            xr[10]=unpl(r1.z); xr[11]=unph(r1.z);
        }
        // x = x @ Wconv[l]
        float xn[DD];
#pragma unroll
        for (int j = 0; j < DD; ++j) xn[j] = 0.f;
#pragma unroll
        for (int i = 0; i < DD; ++i){
            const float4* wr = (const float4*)WcS[l][i];
            float4 w0 = wr[0], w1 = wr[1], w2 = wr[2];
            float xi = xr[i];
            xn[0]=fmaf(xi,w0.x,xn[0]); xn[1]=fmaf(xi,w0.y,xn[1]); xn[2]=fmaf(xi,w0.z,xn[2]); xn[3]=fmaf(xi,w0.w,xn[3]);
            xn[4]=fmaf(xi,w1.x,xn[4]); xn[5]=fmaf(xi,w1.y,xn[5]); xn[6]=fmaf(xi,w1.z,xn[6]); xn[7]=fmaf(xi,w1.w,xn[7]);
            xn[8]=fmaf(xi,w2.x,xn[8]); xn[9]=fmaf(xi,w2.y,xn[9]); xn[10]=fmaf(xi,w2.z,xn[10]); xn[11]=fmaf(xi,w2.w,xn[11]);
        }
#pragma unroll
        for (int j = 0; j < DD; ++j) xr[j] = xn[j];
        // stage x (slots 0-5 = xr[0..5], 8-13 = xr[6..11]; slots 6,7,14,15 zero)
        {
            uint4 s0 = { packh(xr[0],xr[1]), packh(xr[2],xr[3]), packh(xr[4],xr[5]), 0u };
            uint4 s1 = { packh(xr[6],xr[7]), packh(xr[8],xr[9]), packh(xr[10],xr[11]), 0u };
            *(uint4*)(xstS + tid0 * 16) = s0;
            *(uint4*)(xstS + tid0 * 16 + 8) = s1;
        }

#pragma unroll 1
        for (int half = 0; half < 2; ++half){
            const f16* whC = wsh + (size_t)(l * 4 + half * 2) * NLW;
            const f16* wlC = wsl + (size_t)(l * 4 + half * 2) * NLW;
            const f16* whN = whC + NLW;
            const f16* wlN = wlC + NLW;
            const float* b0c = (half ? c2b0 : c1b0) + l * 64;
            const float* bhc = (half ? c2bh : c1bh) + l * 128;
            const float* blc = (half ? c2bl : c1bl) + l * 138;
            const float* b0n = (half ? n2b0 : n1b0) + l * 64;
            const float* bhn = (half ? n2bh : n1bh) + l * 128;
            const float* bln = (half ? n2bl : n1bl) + l * 138;

            // conditioner chain
            gemmL0c(whC, wlC, b0c, xcS, actW, lane, widS);
            gemm64(whC + WS_WH, wlC + WS_WH, bhc, actW, lane);
            gemm64(whC + WS_WH + 4096, wlC + WS_WH + 4096, bhc + 64, actW, lane);
            uint2 tcp[9][4];
            gemmFinC(whC + WS_WL, wlC + WS_WL, blc, actW, lane, tcp);

            // data chain (input = untouched half, from xstage)
            gemmL0n(whN, wlN, b0n, xstS, half * 8, actW, lane, widS);
            gemm64(whN + WS_WH, wlN + WS_WH, bhn, actW, lane);
            gemm64(whN + WS_WH + 4096, wlN + WS_WH + 4096, bhn + 64, actW, lane);
            gemmFinN(whN + WS_WL, wlN + WS_WL, bln, actW, thW, xstS, tcp, lane, widS, half, logdet);
        }
    }

    // final read-back and outputs
    {
        uint4 r0 = *(const uint4*)(xstS + tid0 * 16);
        uint4 r1 = *(const uint4*)(xstS + tid0 * 16 + 8);
        xr[0]=unpl(r0.x); xr[1]=unph(r0.x); xr[2]=unpl(r0.y); xr[3]=unph(r0.y);
        xr[4]=unpl(r0.z); xr[5]=unph(r0.z);
        xr[6]=unpl(r1.x); xr[7]=unph(r1.x); xr[8]=unpl(r1.y); xr[9]=unph(r1.y);
        xr[10]=unpl(r1.z); xr[11]=unph(r1.z);
    }
    float pr = 0.f;
#pragma unroll
    for (int j = 0; j < DD; ++j) pr = fmaf(-0.5f * xr[j], xr[j], pr);
    pr -= DD * 0.91893853320467274f;

    float4* ov = (float4*)(out + (size_t)gsamp * DD);
    ov[0] = make_float4(xr[0], xr[1], xr[2], xr[3]);
    ov[1] = make_float4(xr[4], xr[5], xr[6], xr[7]);
    ov[2] = make_float4(xr[8], xr[9], xr[10], xr[11]);
    out[(size_t)NSAMP * DD + gsamp] = logdet;
    out[(size_t)NSAMP * DD + NSAMP + gsamp] = pr;
}

extern "C" void kernel_launch(void* const* d_in, const int* in_sizes, int n_in,
                              void* d_out, int out_size, void* d_ws, size_t ws_size,
                              hipStream_t stream) {
    (void)in_sizes; (void)n_in; (void)out_size; (void)ws_size;
    const float* a[30];
    for (int i = 0; i < 30; ++i) a[i] = (const float*)d_in[i];
    f16* wsh = (f16*)d_ws;
    f16* wsl = wsh + 16 * NLW;   // needs 16*17920*2 f16 = 1,146,880 B of d_ws

    dim3 pg(70, 16);
    nsflow_prep<<<pg, 256, 0, stream>>>(a[6], a[8], a[10],      // net1 W0,Wh,Wl
                                        a[12], a[14], a[16],    // net2
                                        a[18], a[20], a[22],    // nc1
                                        a[24], a[26], a[28],    // nc2
                                        wsh, wsl);

    nsflow_main<<<NSAMP / BLK, BLK, 0, stream>>>(
        a[0], a[1], a[2], a[3], a[4], a[5],
        a[7], a[9], a[11],      // n1 b0,bh,bl
        a[13], a[15], a[17],    // n2
        a[19], a[21], a[23],    // c1
        a[25], a[27], a[29],    // c2
        wsh, wsl, (float*)d_out);
}

// Round 5
// 310.094 us; speedup vs baseline: 3.2397x; 3.2397x over previous
//
#include <hip/hip_runtime.h>
#include <math.h>

typedef _Float16 f16;
typedef _Float16 f16x8 __attribute__((ext_vector_type(8)));
typedef float f32x4 __attribute__((ext_vector_type(4)));
typedef unsigned int uint32;
typedef unsigned short ushort16;

#define NSAMP 131072
#define DD 12
#define LLAYERS 4
#define KK 8
#define BV 3.0f
#define SLP 0.2f
#define BLK 256
#define NLW 17920   // f16 elems per (net,layer): 512 (W0+b0) + 8192 (Wh) + 9216 (Wl)
#define WS_WH 512
#define WS_WL 8704

__device__ __forceinline__ float leaky(float v){ return v >= 0.f ? v : SLP * v; }

__device__ __forceinline__ uint32 packh(float a, float b){
    union { f16 h; ushort16 u; } x, y;
    x.h = (f16)a; y.h = (f16)b;
    return (uint32)x.u | ((uint32)y.u << 16);
}
__device__ __forceinline__ float unpl(uint32 v){ union { ushort16 u; f16 h; } c; c.u = (ushort16)v; return (float)c.h; }
__device__ __forceinline__ float unph(uint32 v){ union { ushort16 u; f16 h; } c; c.u = (ushort16)(v >> 16); return (float)c.h; }

__device__ __forceinline__ f32x4 MF(f16x8 a, f16x8 b, f32x4 c){
    return __builtin_amdgcn_mfma_f32_16x16x32_f16(a, b, c, 0, 0, 0);
}

// act tile: per-wave [64 samples][64 feats] f16, row=128B, XOR-swizzled by ((s&7)<<4)
__device__ __forceinline__ const f16x8* actRd(const f16* actW, int s, int fb){
    return (const f16x8*)((const char*)actW + s * 128 + (fb ^ ((s & 7) << 4)));
}
__device__ __forceinline__ uint2* actWr(f16* actW, int s, int fb){
    return (uint2*)((char*)actW + s * 128 + (fb ^ ((s & 7) << 4)));
}

// ---------------- prep: weights -> fp16 hi/lo fragments; fold L0 bias (k=7 row);
// pack final-layer biases as half2 (cond lo, net hi) into wsbc ----------------
extern "C" __global__ void nsflow_prep(
        const float* __restrict__ n1W0, const float* __restrict__ n1Wh, const float* __restrict__ n1Wl,
        const float* __restrict__ n1b0, const float* __restrict__ n1bl,
        const float* __restrict__ n2W0, const float* __restrict__ n2Wh, const float* __restrict__ n2Wl,
        const float* __restrict__ n2b0, const float* __restrict__ n2bl,
        const float* __restrict__ c1W0, const float* __restrict__ c1Wh, const float* __restrict__ c1Wl,
        const float* __restrict__ c1b0, const float* __restrict__ c1bl,
        const float* __restrict__ c2W0, const float* __restrict__ c2Wh, const float* __restrict__ c2Wl,
        const float* __restrict__ c2b0, const float* __restrict__ c2bl,
        f16* __restrict__ ws_hi, f16* __restrict__ ws_lo, uint32* __restrict__ wsbc){
    int NL = blockIdx.y;                      // l*4 + net; net: 0=c1 1=n1 2=c2 3=n2
    int off = blockIdx.x * 256 + threadIdx.x;
    int layer = NL >> 2, net = NL & 3;

    if (off >= 17920){                        // final-bias pack region
        int f = off - 17920;
        if (f >= 144) return;
        if (net == 0){
            float cf = f < 138 ? c1bl[layer * 138 + f] : 0.f;
            float nf = f < 138 ? n1bl[layer * 138 + f] : 0.f;
            wsbc[(layer * 2 + 0) * 144 + f] = packh(cf, nf);
        } else if (net == 2){
            float cf = f < 138 ? c2bl[layer * 138 + f] : 0.f;
            float nf = f < 138 ? n2bl[layer * 138 + f] : 0.f;
            wsbc[(layer * 2 + 1) * 144 + f] = packh(cf, nf);
        }
        return;
    }

    const float *W0, *Wh, *Wl, *b0; int nin;
    if (net == 0){ W0 = c1W0; Wh = c1Wh; Wl = c1Wl; b0 = c1b0; nin = 4; }
    else if (net == 1){ W0 = n1W0; Wh = n1Wh; Wl = n1Wl; b0 = n1b0; nin = 6; }
    else if (net == 2){ W0 = c2W0; Wh = c2Wh; Wl = c2Wl; b0 = c2b0; nin = 4; }
    else { W0 = n2W0; Wh = n2Wh; Wl = n2Wl; b0 = n2b0; nin = 6; }

    float w = 0.f;
    if (off < 512){                          // W0^T frags: [mt(4)][16 lanes][8 j]; j==7 -> bias
        int mt = off >> 7, r = off & 127, ln = r >> 3, j = r & 7;
        int row = mt * 16 + ln;
        if (j < nin) w = W0[(layer * nin + j) * 64 + row];
        else if (j == 7) w = b0[layer * 64 + row];
    } else if (off < 8704){                  // Wh^T frags: [h(2)][mt*2+ks (8)][64 lanes][8 j]
        int o = off - 512; int h = o >> 12; o &= 4095;
        int t = o >> 9, ln = (o >> 3) & 63, j = o & 7;
        int mt = t >> 1, ks = t & 1;
        int k = ks * 32 + (ln >> 4) * 8 + j, row = mt * 16 + (ln & 15);
        w = Wh[((layer * 2 + h) * 64 + k) * 64 + row];
    } else {                                 // Wl^T frags: [mt*2+ks (18)][64 lanes][8 j]
        int o = off - 8704;
        int t = o >> 9, ln = (o >> 3) & 63, j = o & 7;
        int mt = t >> 1, ks = t & 1;
        int k = ks * 32 + (ln >> 4) * 8 + j, row = mt * 16 + (ln & 15);
        if (row < 138) w = Wl[(layer * 64 + k) * 138 + row];
    }
    f16 hi = (f16)w;
    f16 lo = (f16)(w - (float)hi);
    ws_hi[NL * NLW + off] = hi;
    ws_lo[NL * NLW + off] = lo;
}

// ---------------- GEMM helpers ----------------
// first layer, conditioner: B built by shuffle from per-thread xc regs; bias folded (B slot7=1)
__device__ __forceinline__ void gemmL0c(const f16* __restrict__ ah, const f16* __restrict__ al,
                                        int xc0, int xc1, f16* actW, int lane){
    int l15 = lane & 15, g = lane >> 4;
    f16x8 Z = {};
    f16x8 Bf[4];
#pragma unroll
    for (int nt = 0; nt < 4; ++nt){
        union { uint4 u; f16x8 v; } cc;
        cc.u.x = (uint32)__shfl(xc0, nt * 16 + l15, 64);
        cc.u.y = (uint32)__shfl(xc1, nt * 16 + l15, 64);
        cc.u.z = 0u;
        cc.u.w = 0x3C000000u;   // slots 6,7 = (0, 1.0h)
        Bf[nt] = cc.v;
    }
    bool g0 = (g == 0);
#pragma unroll
    for (int mt = 0; mt < 4; ++mt){
        f16x8 Ah = g0 ? *(const f16x8*)(ah + (mt * 16 + l15) * 8) : Z;
        f16x8 Al = g0 ? *(const f16x8*)(al + (mt * 16 + l15) * 8) : Z;
#pragma unroll
        for (int nt = 0; nt < 4; ++nt){
            f32x4 acc = {0.f, 0.f, 0.f, 0.f};
            acc = MF(Ah, Bf[nt], acc);
            acc = MF(Al, Bf[nt], acc);
            uint2 v = { packh(leaky(acc[0]), leaky(acc[1])), packh(leaky(acc[2]), leaky(acc[3])) };
            *actWr(actW, nt * 16 + l15, mt * 32 + g * 8) = v;
        }
    }
}

// first layer, data net: B from xstS rows (bias folded, slot 7/15 = 1.0)
__device__ __forceinline__ void gemmL0n(const f16* __restrict__ ah, const f16* __restrict__ al,
                                        const f16* src, int offE,
                                        f16* actW, int lane, int widS){
    int l15 = lane & 15, g = lane >> 4;
    f16x8 Z = {};
    f16x8 Bf[4];
#pragma unroll
    for (int nt = 0; nt < 4; ++nt)
        Bf[nt] = *(const f16x8*)(src + (widS + nt * 16 + l15) * 16 + offE);
    bool g0 = (g == 0);
#pragma unroll
    for (int mt = 0; mt < 4; ++mt){
        f16x8 Ah = g0 ? *(const f16x8*)(ah + (mt * 16 + l15) * 8) : Z;
        f16x8 Al = g0 ? *(const f16x8*)(al + (mt * 16 + l15) * 8) : Z;
#pragma unroll
        for (int nt = 0; nt < 4; ++nt){
            f32x4 acc = {0.f, 0.f, 0.f, 0.f};
            acc = MF(Ah, Bf[nt], acc);
            acc = MF(Al, Bf[nt], acc);
            uint2 v = { packh(leaky(acc[0]), leaky(acc[1])), packh(leaky(acc[2]), leaky(acc[3])) };
            *actWr(actW, nt * 16 + l15, mt * 32 + g * 8) = v;
        }
    }
}

// hidden 64->64, in place (B fragments pre-loaded before first write)
__device__ __forceinline__ void gemm64(const f16* __restrict__ ah, const f16* __restrict__ al,
                                       const float* __restrict__ bias,
                                       f16* actW, int lane){
    int l15 = lane & 15, g = lane >> 4;
    f16x8 Bf[4][2];
#pragma unroll
    for (int nt = 0; nt < 4; ++nt)
#pragma unroll
        for (int ks = 0; ks < 2; ++ks)
            Bf[nt][ks] = *actRd(actW, nt * 16 + l15, ks * 64 + g * 16);
#pragma unroll
    for (int mt = 0; mt < 4; ++mt){
        f16x8 Ah0 = *(const f16x8*)(ah + ((mt * 2 + 0) * 64 + lane) * 8);
        f16x8 Ah1 = *(const f16x8*)(ah + ((mt * 2 + 1) * 64 + lane) * 8);
        f16x8 Al0 = *(const f16x8*)(al + ((mt * 2 + 0) * 64 + lane) * 8);
        f16x8 Al1 = *(const f16x8*)(al + ((mt * 2 + 1) * 64 + lane) * 8);
        float b0v = bias[mt * 16 + g * 4 + 0];
        float b1v = bias[mt * 16 + g * 4 + 1];
        float b2v = bias[mt * 16 + g * 4 + 2];
        float b3v = bias[mt * 16 + g * 4 + 3];
#pragma unroll
        for (int nt = 0; nt < 4; ++nt){
            f32x4 acc = {0.f, 0.f, 0.f, 0.f};
            acc = MF(Ah0, Bf[nt][0], acc);
            acc = MF(Al0, Bf[nt][0], acc);
            acc = MF(Ah1, Bf[nt][1], acc);
            acc = MF(Al1, Bf[nt][1], acc);
            uint2 v = { packh(leaky(acc[0] + b0v), leaky(acc[1] + b1v)),
                        packh(leaky(acc[2] + b2v), leaky(acc[3] + b3v)) };
            *actWr(actW, nt * 16 + l15, mt * 32 + g * 8) = v;
        }
    }
}

// epilogue of fused finals: t = leaky(net+bn)*leaky(cond+bc) -> thW (spline layout)
__device__ __forceinline__ void emit4(f16* thW, int crow, f32x4 ac, f32x4 an,
                                      uint4 bq, int mt, int g4){
#pragma unroll
    for (int i = 0; i < 4; ++i){
        uint32 bb = (i == 0) ? bq.x : (i == 1) ? bq.y : (i == 2) ? bq.z : bq.w;
        float tcv = leaky(ac[i] + unpl(bb));
        float tnv = leaky(an[i] + unph(bb));
        float tv = tcv * tnv;
        int f = mt * 16 + g4 + i;
        if (f < 138){
            int dd = (f * 357) >> 13;
            int p = f - dd * 23;
            thW[crow * 144 + dd * 24 + p] = (f16)tv;
        }
    }
}

// spline for one chunk of 16 samples; lane L ends with 6-dim logdet sum for sample sbase+(L&15)
__device__ __forceinline__ float spline_chunk(const f16* thW, f16* xst,
                                              int sbase, int half, int lane){
    float vsum = 0.f;
#pragma unroll 1
    for (int pass = 0; pass < 2; ++pass){
        if (pass == 1 && lane >= 32) break;
        int dd = pass * 4 + (lane >> 4);
        int s16 = lane & 15;

        const f16* tr = thW + s16 * 144 + dd * 24;
        f16x8 t0 = *(const f16x8*)(tr);
        f16x8 t1 = *(const f16x8*)(tr + 8);
        f16x8 t2 = *(const f16x8*)(tr + 16);
        float th[23];
#pragma unroll
        for (int j = 0; j < 8; ++j) th[j] = (float)t0[j];
#pragma unroll
        for (int j = 0; j < 8; ++j) th[8 + j] = (float)t1[j];
#pragma unroll
        for (int j = 0; j < 7; ++j) th[16 + j] = (float)t2[j];

        float mw = th[0];
#pragma unroll
        for (int j = 1; j < KK; ++j) mw = fmaxf(mw, th[j]);
        float ew[KK]; float swsum = 0.f;
#pragma unroll
        for (int j = 0; j < KK; ++j){ ew[j] = __expf(th[j] - mw); swsum += ew[j]; }
        float iw_ = 6.0f / swsum;
        float mh = th[KK];
#pragma unroll
        for (int j = 1; j < KK; ++j) mh = fmaxf(mh, th[KK + j]);
        float eh[KK]; float shsum = 0.f;
#pragma unroll
        for (int j = 0; j < KK; ++j){ eh[j] = __expf(th[KK + j] - mh); shsum += eh[j]; }
        float ih_ = 6.0f / shsum;
        float dv[KK + 1];
        dv[0] = 1.0f; dv[KK] = 1.0f;
#pragma unroll
        for (int j = 0; j < KK - 1; ++j){
            float v = th[2 * KK + j];
            float z = __expf(-fabsf(v));
            dv[j + 1] = fmaxf(v, 0.f) + __logf(1.0f + z);
        }

        int sidx = sbase + s16;
        int slot = half ? dd : 8 + dd;
        float X = (float)xst[sidx * 16 + slot];
        float Xc = fminf(fmaxf(X, -BV), BV);

        float cx = -BV, cy = -BV;
        float xk = -BV, xk1 = BV, yk = -BV, yk1 = BV, dk = 1.0f, dk1 = 1.0f;
#pragma unroll
        for (int j = 0; j < KK; ++j){
            float nx = (j == KK - 1) ? (BV + 1e-6f) : (cx + ew[j] * iw_);
            float ny = (j == KK - 1) ? BV : (cy + eh[j] * ih_);
            bool sel = (j == 0) || (Xc >= cx);
            if (sel){ xk = cx; xk1 = nx; yk = cy; yk1 = ny; dk = dv[j]; dk1 = dv[j + 1]; }
            cx = nx; cy = ny;
        }
        float idx_ = 1.0f / (xk1 - xk);
        float s_ = (yk1 - yk) * idx_;
        float xi = (Xc - xk) * idx_;
        float om = 1.0f - xi;
        float xo = xi * om;
        float den = s_ + (dk1 + dk - 2.0f * s_) * xo;
        float Y = yk + (yk1 - yk) * (s_ * xi * xi + dk * xo) / den;
        float dydx = s_ * s_ * (dk1 * xi * xi + 2.0f * s_ * xo + dk * om * om) / (den * den);
        bool inside = (X <= BV) && (X >= -BV);
        float Yo = inside ? Y : X;
        float ldv = inside ? __logf(dydx) : 0.f;
        xst[sidx * 16 + slot] = (f16)Yo;
        vsum += ldv;
    }
    vsum += __shfl_xor(vsum, 16, 64);
    vsum += __shfl_xor(vsum, 32, 64);
    return vsum;
}

// one tail pass: 2 chunks (NT0, NT1); per-mt fused cond+net finals, then 2 splines.
// No persistent per-lane output array — rule #20 / R4 spill post-mortem.
#define TAILP(NT0, NT1, BCA0, BCB0, BCA1, BCB1)                                        \
{                                                                                      \
    f16x8 Bn0a = *actRd(actW, NT0 * 16 + l15, g * 16);                                 \
    f16x8 Bn0b = *actRd(actW, NT0 * 16 + l15, 64 + g * 16);                            \
    f16x8 Bn1a = *actRd(actW, NT1 * 16 + l15, g * 16);                                 \
    f16x8 Bn1b = *actRd(actW, NT1 * 16 + l15, 64 + g * 16);                            \
    _Pragma("unroll")                                                                  \
    for (int mt = 0; mt < 9; ++mt){                                                    \
        const f16* pch = whC + WS_WL + (mt * 128 + lane) * 8;                          \
        const f16* pcl = wlC + WS_WL + (mt * 128 + lane) * 8;                          \
        const f16* pnh = whN + WS_WL + (mt * 128 + lane) * 8;                          \
        const f16* pnl = wlN + WS_WL + (mt * 128 + lane) * 8;                          \
        f16x8 AhC0 = *(const f16x8*)(pch);                                             \
        f16x8 AhC1 = *(const f16x8*)(pch + 512);                                       \
        f16x8 AlC0 = *(const f16x8*)(pcl);                                             \
        f16x8 AlC1 = *(const f16x8*)(pcl + 512);                                       \
        f16x8 AhN0 = *(const f16x8*)(pnh);                                             \
        f16x8 AhN1 = *(const f16x8*)(pnh + 512);                                       \
        f16x8 AlN0 = *(const f16x8*)(pnl);                                             \
        f16x8 AlN1 = *(const f16x8*)(pnl + 512);                                       \
        uint4 bq = *(const uint4*)(bcn + mt * 16 + g4);                                \
        f32x4 ac = {0.f,0.f,0.f,0.f}, an = {0.f,0.f,0.f,0.f};                          \
        ac = MF(AhC0, BCA0, ac); ac = MF(AlC0, BCA0, ac);                              \
        ac = MF(AhC1, BCB0, ac); ac = MF(AlC1, BCB0, ac);                              \
        an = MF(AhN0, Bn0a, an); an = MF(AlN0, Bn0a, an);                              \
        an = MF(AhN1, Bn0b, an); an = MF(AlN1, Bn0b, an);                              \
        emit4(thW, l15, ac, an, bq, mt, g4);                                           \
        f32x4 ac2 = {0.f,0.f,0.f,0.f}, an2 = {0.f,0.f,0.f,0.f};                        \
        ac2 = MF(AhC0, BCA1, ac2); ac2 = MF(AlC0, BCA1, ac2);                          \
        ac2 = MF(AhC1, BCB1, ac2); ac2 = MF(AlC1, BCB1, ac2);                          \
        an2 = MF(AhN0, Bn1a, an2); an2 = MF(AlN0, Bn1a, an2);                          \
        an2 = MF(AhN1, Bn1b, an2); an2 = MF(AlN1, Bn1b, an2);                          \
        emit4(thW, 16 + l15, ac2, an2, bq, mt, g4);                                    \
    }                                                                                  \
    { float v = spline_chunk(thW, xstS, widS + NT0 * 16, half, lane);                  \
      if (g == NT0) logdet += v; }                                                     \
    { float v = spline_chunk(thW + 16 * 144, xstS, widS + NT1 * 16, half, lane);       \
      if (g == NT1) logdet += v; }                                                     \
}

// ---------------- main kernel ----------------
extern "C" __global__ void __launch_bounds__(BLK, 2)
nsflow_main(const float* __restrict__ x_in, const float* __restrict__ xc_in,
            const float* __restrict__ convP, const float* __restrict__ convS,
            const float* __restrict__ convL, const float* __restrict__ convU,
            const float* __restrict__ n1bh, const float* __restrict__ n2bh,
            const float* __restrict__ c1bh, const float* __restrict__ c2bh,
            const f16* __restrict__ wsh, const f16* __restrict__ wsl,
            const uint32* __restrict__ wsbc,
            float* __restrict__ out){
    __shared__ float WcS[LLAYERS][DD][DD];
    __shared__ float ldcS;
    __shared__ f16 xstS[256 * 16];
    __shared__ f16 actS[4 * 64 * 64];
    __shared__ f16 thS[4 * 32 * 144];

    for (int e = threadIdx.x; e < LLAYERS * DD * DD; e += BLK){
        int l = e / (DD * DD);
        int r = e - l * DD * DD;
        int i = r / DD;
        int j = r - i * DD;
        const float* P = convP + l * DD * DD;
        const float* Lm = convL + l * DD * DD;
        const float* Um = convU + l * DD * DD;
        const float* Sv = convS + l * DD;
        float acc = 0.f;
        for (int a = 0; a < DD; ++a){
            float inner = 0.f;
            for (int bb = 0; bb < DD; ++bb){
                float m1 = (bb < a) ? Lm[a * DD + bb] : (bb == a ? 1.f : 0.f);
                float m2 = (j > bb) ? Um[bb * DD + j] : (j == bb ? Sv[j] : 0.f);
                inner = fmaf(m1, m2, inner);
            }
            acc = fmaf(P[i * DD + a], inner, acc);
        }
        WcS[l][i][j] = acc;
    }
    if (threadIdx.x == 0){
        float sacc = 0.f;
        for (int q = 0; q < LLAYERS * DD; ++q) sacc += __logf(fabsf(convS[q]));
        ldcS = sacc;
    }

    int tid0 = threadIdx.x;
    int lane = tid0 & 63, wid = tid0 >> 6, widS = wid * 64;
    int l15 = lane & 15, g = lane >> 4, g4 = g * 4;
    int gsamp = blockIdx.x * BLK + tid0;

    float xr[DD];
    int xc0, xc1;
    {
        const float4* xv = (const float4*)(x_in + (size_t)gsamp * DD);
        float4 a0 = xv[0], a1 = xv[1], a2 = xv[2];
        xr[0]=a0.x; xr[1]=a0.y; xr[2]=a0.z; xr[3]=a0.w;
        xr[4]=a1.x; xr[5]=a1.y; xr[6]=a1.z; xr[7]=a1.w;
        xr[8]=a2.x; xr[9]=a2.y; xr[10]=a2.z; xr[11]=a2.w;
        float4 c0 = *(const float4*)(xc_in + (size_t)gsamp * 4);
        xc0 = (int)packh(c0.x, c0.y);
        xc1 = (int)packh(c0.z, c0.w);
    }
    __syncthreads();

    float logdet = ldcS;
    f16* actW = actS + wid * 4096;
    f16* thW = thS + wid * 4608;

#pragma unroll 1
    for (int l = 0; l < LLAYERS; ++l){
        if (l > 0){
            uint4 r0 = *(const uint4*)(xstS + tid0 * 16);
            uint4 r1 = *(const uint4*)(xstS + tid0 * 16 + 8);
            xr[0]=unpl(r0.x); xr[1]=unph(r0.x); xr[2]=unpl(r0.y); xr[3]=unph(r0.y);
            xr[4]=unpl(r0.z); xr[5]=unph(r0.z);
            xr[6]=unpl(r1.x); xr[7]=unph(r1.x); xr[8]=unpl(r1.y); xr[9]=unph(r1.y);
            xr[10]=unpl(r1.z); xr[11]=unph(r1.z);
        }
        float xn[DD];
#pragma unroll
        for (int j = 0; j < DD; ++j) xn[j] = 0.f;
#pragma unroll
        for (int i = 0; i < DD; ++i){
            const float4* wr = (const float4*)WcS[l][i];
            float4 w0 = wr[0], w1 = wr[1], w2 = wr[2];
            float xi = xr[i];
            xn[0]=fmaf(xi,w0.x,xn[0]); xn[1]=fmaf(xi,w0.y,xn[1]); xn[2]=fmaf(xi,w0.z,xn[2]); xn[3]=fmaf(xi,w0.w,xn[3]);
            xn[4]=fmaf(xi,w1.x,xn[4]); xn[5]=fmaf(xi,w1.y,xn[5]); xn[6]=fmaf(xi,w1.z,xn[6]); xn[7]=fmaf(xi,w1.w,xn[7]);
            xn[8]=fmaf(xi,w2.x,xn[8]); xn[9]=fmaf(xi,w2.y,xn[9]); xn[10]=fmaf(xi,w2.z,xn[10]); xn[11]=fmaf(xi,w2.w,xn[11]);
        }
#pragma unroll
        for (int j = 0; j < DD; ++j) xr[j] = xn[j];
        // stage x: slots 0-5 = xr[0..5], 8-13 = xr[6..11]; slots 7,15 = 1.0 (bias-fold input)
        {
            uint4 s0 = { packh(xr[0],xr[1]), packh(xr[2],xr[3]), packh(xr[4],xr[5]), 0x3C000000u };
            uint4 s1 = { packh(xr[6],xr[7]), packh(xr[8],xr[9]), packh(xr[10],xr[11]), 0x3C000000u };
            *(uint4*)(xstS + tid0 * 16) = s0;
            *(uint4*)(xstS + tid0 * 16 + 8) = s1;
        }

#pragma unroll 1
        for (int half = 0; half < 2; ++half){
            const f16* whC = wsh + (size_t)(l * 4 + half * 2) * NLW;
            const f16* wlC = wsl + (size_t)(l * 4 + half * 2) * NLW;
            const f16* whN = whC + NLW;
            const f16* wlN = wlC + NLW;
            const float* bhc = (half ? c2bh : c1bh) + l * 128;
            const float* bhn = (half ? n2bh : n1bh) + l * 128;
            const uint32* bcn = wsbc + (l * 2 + half) * 144;

            // conditioner chain
            gemmL0c(whC, wlC, xc0, xc1, actW, lane);
            gemm64(whC + WS_WH, wlC + WS_WH, bhc, actW, lane);
            gemm64(whC + WS_WH + 4096, wlC + WS_WH + 4096, bhc + 64, actW, lane);
            // snapshot conditioner final-hidden B fragments (32 VGPRs)
            f16x8 Bc0a = *actRd(actW,      l15, g * 16);
            f16x8 Bc0b = *actRd(actW,      l15, 64 + g * 16);
            f16x8 Bc1a = *actRd(actW, 16 + l15, g * 16);
            f16x8 Bc1b = *actRd(actW, 16 + l15, 64 + g * 16);
            f16x8 Bc2a = *actRd(actW, 32 + l15, g * 16);
            f16x8 Bc2b = *actRd(actW, 32 + l15, 64 + g * 16);
            f16x8 Bc3a = *actRd(actW, 48 + l15, g * 16);
            f16x8 Bc3b = *actRd(actW, 48 + l15, 64 + g * 16);

            // data chain (overwrites actW)
            gemmL0n(whN, wlN, xstS, half * 8, actW, lane, widS);
            gemm64(whN + WS_WH, wlN + WS_WH, bhn, actW, lane);
            gemm64(whN + WS_WH + 4096, wlN + WS_WH + 4096, bhn + 64, actW, lane);

            // fused finals + splines, 2 chunks per pass
            TAILP(0, 1, Bc0a, Bc0b, Bc1a, Bc1b)
            TAILP(2, 3, Bc2a, Bc2b, Bc3a, Bc3b)
        }
    }

    {
        uint4 r0 = *(const uint4*)(xstS + tid0 * 16);
        uint4 r1 = *(const uint4*)(xstS + tid0 * 16 + 8);
        xr[0]=unpl(r0.x); xr[1]=unph(r0.x); xr[2]=unpl(r0.y); xr[3]=unph(r0.y);
        xr[4]=unpl(r0.z); xr[5]=unph(r0.z);
        xr[6]=unpl(r1.x); xr[7]=unph(r1.x); xr[8]=unpl(r1.y); xr[9]=unph(r1.y);
        xr[10]=unpl(r1.z); xr[11]=unph(r1.z);
    }
    float pr = 0.f;
#pragma unroll
    for (int j = 0; j < DD; ++j) pr = fmaf(-0.5f * xr[j], xr[j], pr);
    pr -= DD * 0.91893853320467274f;

    float4* ov = (float4*)(out + (size_t)gsamp * DD);
    ov[0] = make_float4(xr[0], xr[1], xr[2], xr[3]);
    ov[1] = make_float4(xr[4], xr[5], xr[6], xr[7]);
    ov[2] = make_float4(xr[8], xr[9], xr[10], xr[11]);
    out[(size_t)NSAMP * DD + gsamp] = logdet;
    out[(size_t)NSAMP * DD + NSAMP + gsamp] = pr;
}

extern "C" void kernel_launch(void* const* d_in, const int* in_sizes, int n_in,
                              void* d_out, int out_size, void* d_ws, size_t ws_size,
                              hipStream_t stream) {
    (void)in_sizes; (void)n_in; (void)out_size; (void)ws_size;
    const float* a[30];
    for (int i = 0; i < 30; ++i) a[i] = (const float*)d_in[i];
    f16* wsh = (f16*)d_ws;
    f16* wsl = wsh + 16 * NLW;
    uint32* wsbc = (uint32*)(wsl + 16 * NLW);   // total ws: 2*16*17920*2 + 8*144*4 = 1,151,488 B

    dim3 pg(71, 16);
    nsflow_prep<<<pg, 256, 0, stream>>>(
        a[6], a[8], a[10], a[7], a[11],     // net1 W0,Wh,Wl,b0,bl
        a[12], a[14], a[16], a[13], a[17],  // net2
        a[18], a[20], a[22], a[19], a[23],  // nc1
        a[24], a[26], a[28], a[25], a[29],  // nc2
        wsh, wsl, wsbc);

    nsflow_main<<<NSAMP / BLK, BLK, 0, stream>>>(
        a[0], a[1], a[2], a[3], a[4], a[5],
        a[9], a[15], a[21], a[27],          // n1bh, n2bh, c1bh, c2bh
        wsh, wsl, wsbc, (float*)d_out);
}